// Round 3
// baseline (598.926 us; speedup 1.0000x reference)
//
#include <hip/hip_runtime.h>
#include <hip/hip_bf16.h>
#include <math.h>

// Problem: B=8, S=512, V=32000, M=32, PAD_ID=1
// logp[b,s] = logits[b,s,a[b,s]] - logsumexp_{m: mask[b,s,m]>0}(logits[b,s,mask[b,s,m]])
// out[b] = sum_s logp[b,s] * (a[b,s] != 1)
// Softmax Z cancels in p_a/base -> never touch the V dimension (524 MB -> ~9 MB).
//
// Shape: 8 blocks (one per b) x 512 threads -> ONE THREAD PER POSITION.
// Per thread: 8x int4 mask-index load (128 B contiguous per lane), then all
// 33 logit gathers issued unconditionally back-to-back (invalid idx -> 0,
// masked in ALU) => 33 independent HBM loads in flight per lane, a single
// latency exposure instead of a serialized loop. Reduction is register-local;
// one wave-shuffle reduce + tiny LDS reduce per block; plain store, no atomics.

#define BB 8
#define SS 512
#define VV 32000
#define MM 32

__global__ __launch_bounds__(512) void logp_kernel(
    const float* __restrict__ logits,   // [B*S, V]
    const int*   __restrict__ a,        // [B*S]
    const int*   __restrict__ mask,     // [B*S, M]
    float*       __restrict__ out)      // [B]
{
    const int b   = blockIdx.x;             // 0..7
    const int t   = threadIdx.x;            // 0..511  == s
    const int pos = b * SS + t;

    const float* __restrict__ row = logits + (size_t)pos * VV;

    // ---- load indices: action id + 32 mask ids (8 x int4, 128 B/lane) ----
    const int a_id = a[pos];
    int m[MM];
    const int4* __restrict__ mrow = reinterpret_cast<const int4*>(mask + (size_t)pos * MM);
    #pragma unroll
    for (int q = 0; q < MM / 4; ++q) {
        const int4 v = mrow[q];
        m[4 * q + 0] = v.x; m[4 * q + 1] = v.y;
        m[4 * q + 2] = v.z; m[4 * q + 3] = v.w;
    }

    // ---- issue all gathers unconditionally (max ILP) ----
    float x[MM];
    #pragma unroll
    for (int j = 0; j < MM; ++j) {
        const int idx = (m[j] > 0) ? m[j] : 0;   // safe addr; masked below
        x[j] = row[idx];
    }
    const float logit_a = row[a_id];

    // ---- register-local logsumexp over valid entries ----
    float mx = -INFINITY;
    #pragma unroll
    for (int j = 0; j < MM; ++j)
        mx = fmaxf(mx, (m[j] > 0) ? x[j] : -INFINITY);

    float e = 0.0f;
    #pragma unroll
    for (int j = 0; j < MM; ++j)
        e += (m[j] > 0) ? expf(x[j] - mx) : 0.0f;

    const float lse  = mx + logf(e);
    float logp = (a_id != 1) ? (logit_a - lse) : 0.0f;

    // ---- block reduction: 64-lane butterfly, then 8-wave LDS reduce ----
    #pragma unroll
    for (int off = 32; off; off >>= 1)
        logp += __shfl_xor(logp, off, 64);

    __shared__ float wsum[8];
    const int wave = t >> 6;
    if ((t & 63) == 0) wsum[wave] = logp;
    __syncthreads();
    if (t == 0) {
        float s = 0.0f;
        #pragma unroll
        for (int w = 0; w < 8; ++w) s += wsum[w];
        out[b] = s;
    }
}

extern "C" void kernel_launch(void* const* d_in, const int* in_sizes, int n_in,
                              void* d_out, int out_size, void* d_ws, size_t ws_size,
                              hipStream_t stream) {
    const float* logits = (const float*)d_in[0];
    const int*   a      = (const int*)d_in[1];
    const int*   mask   = (const int*)d_in[2];
    float*       out    = (float*)d_out;

    logp_kernel<<<BB, SS, 0, stream>>>(logits, a, mask, out);
}